// Round 11
// baseline (178.563 us; speedup 1.0000x reference)
//
#include <hip/hip_runtime.h>

#define NPTS 2048
#define TPB  768    // 12 waves/block; 2 own cells/thread; capacity 1536

typedef float v2f __attribute__((ext_vector_type(2)));

// Barrier WITHOUT the vmcnt(0) drain __syncthreads() would emit:
// LDS writes must be visible (lgkmcnt), global stores may stay in flight.
#define EDGE_BARRIER() do {                                   \
    asm volatile("s_waitcnt lgkmcnt(0)" ::: "memory");        \
    __builtin_amdgcn_s_barrier();                             \
    asm volatile("" ::: "memory");                            \
} while (0)

__device__ __forceinline__ v2f s2(float x) { v2f v; v.x = x; v.y = x; return v; }

__device__ __forceinline__ v2f fma2(v2f a, v2f b, v2f c) {
#if __has_builtin(__builtin_elementwise_fma)
    return __builtin_elementwise_fma(a, b, c);
#else
    v2f r; r.x = fmaf(a.x, b.x, c.x); r.y = fmaf(a.y, b.y, c.y); return r;
#endif
}

// g = 0.5*f(u) = u*(0.75 + u*(9.375 + u*(-25.25 + u*(18.75 - 3.125 u^2))))
// p = f'(u)    = 1.5 + u*(37.5 + u*(-151.5 + u*(150 - 37.5 u^2)))
__device__ __forceinline__ void eval_gp2(v2f u, v2f& g, v2f& p) {
    const v2f uu = u * u;
    v2f gg = fma2(uu, s2(-3.125f), s2(18.75f));
    gg = fma2(u, gg, s2(-25.25f));
    gg = fma2(u, gg, s2(9.375f));
    gg = fma2(u, gg, s2(0.75f));
    g = u * gg;
    v2f pp = fma2(uu, s2(-37.5f), s2(150.0f));
    pp = fma2(u, pp, s2(-151.5f));
    pp = fma2(u, pp, s2(37.5f));
    p = fma2(u, pp, s2(1.5f));
}

// Grid = 2 blocks per row. Block (r,h) evolves 1536 cells (own 1024 + 512
// ghost wedge); clamp junk advances 1 cell/step -> own cells exact at t<=499.
// SUPER-STEP: each thread reads neighbors' (u,g,p) pairs -> 6-cell window,
// advances TWO timesteps autonomously (redundant overlap cells are computed
// bit-identically by adjacent threads), one barrier per 2 steps.
__global__ __launch_bounds__(TPB) void lxf_split(
    const float* __restrict__ init, float* __restrict__ out,
    int nbatch, int nsteps)
{
    __shared__ v2f Us[2][TPB];
    __shared__ v2f Gs[2][TPB];
    __shared__ v2f Ps[2][TPB];

    const int blk = blockIdx.x;
    const int r   = blk >> 1;            // row
    const int h   = blk & 1;             // 0 -> global [0,1536), 1 -> [512,2048)
    const int tid = threadIdx.x;
    const int c0  = 2 * tid;             // local first cell
    const int gb  = h ? 512 : 0;
    const size_t rowoff = (size_t)r * NPTS;
    const float lam = 0.1024f;           // DT/DX (exact in f32)

    const bool st  = h ? (c0 >= 512) : (c0 < 1024);      // own-cell store mask
    const bool bcL = (h == 0) && (tid == 0);             // global cell 0
    const bool bcR = (h == 1) && (tid == TPB - 1);       // global cell 2047
    const int  tl  = (tid == 0)       ? 0   : tid - 1;
    const int  tr  = (tid == TPB - 1) ? tid : tid + 1;
    const int dist = h ? (509 - c0) : (c0 - 1025);       // wedge cone distance

    // ---- load init, eval g/p, write t=0, publish buf 0 ----
    v2f uv = *reinterpret_cast<const v2f*>(init + rowoff + gb + c0);
    v2f gv, pv;
    eval_gp2(uv, gv, pv);

    if (st) *reinterpret_cast<v2f*>(out + rowoff + gb + c0) = uv;

    Us[0][tid] = uv; Gs[0][tid] = gv; Ps[0][tid] = pv;
    EDGE_BARRIER();

    const size_t stride = (size_t)nbatch * NPTS;    // floats per step
    float* dstw = out + rowoff + gb + c0;           // points at last-written row

#define FLUX(gl, gr, pl, pr, ul, ur) \
    fmaf(-0.5f * fmaxf(fabsf(pl), fabsf(pr)), (ur) - (ul), (gl) + (gr))

// Two timesteps, one barrier. Window cells c0-2..c0+3 (u,g,p) from LDS.
#define SUPER(CUR, NXT) do {                                               \
    dstw += 2 * stride;                                                    \
    if (dist <= rem) {                                                     \
        const v2f uLp = Us[CUR][tl], gLp = Gs[CUR][tl], pLp = Ps[CUR][tl]; \
        const v2f uRp = Us[CUR][tr], gRp = Gs[CUR][tr], pRp = Ps[CUR][tr]; \
        float yu[6], yg[6], yp[6];                                         \
        yu[0]=uLp.x; yu[1]=uLp.y; yu[2]=uv.x; yu[3]=uv.y; yu[4]=uRp.x; yu[5]=uRp.y; \
        yg[0]=gLp.x; yg[1]=gLp.y; yg[2]=gv.x; yg[3]=gv.y; yg[4]=gRp.x; yg[5]=gRp.y; \
        yp[0]=pLp.x; yp[1]=pLp.y; yp[2]=pv.x; yp[3]=pv.y; yp[4]=pRp.x; yp[5]=pRp.y; \
        if (tid == 0) {                                                    \
            yu[0]=uv.x; yu[1]=uv.x; yg[0]=gv.x; yg[1]=gv.x;                \
            yp[0]=pv.x; yp[1]=pv.x;                                        \
        }                                                                  \
        if (tid == TPB - 1) {                                              \
            yu[4]=uv.y; yu[5]=uv.y; yg[4]=gv.y; yg[5]=gv.y;                \
            yp[4]=pv.y; yp[5]=pv.y;                                        \
        }                                                                  \
        /* step 1: update cells c0-1 .. c0+2 */                            \
        float F[5];                                                        \
        _Pragma("unroll")                                                  \
        for (int j = 0; j < 5; ++j)                                        \
            F[j] = FLUX(yg[j], yg[j+1], yp[j], yp[j+1], yu[j], yu[j+1]);   \
        float z0 = fmaf(-lam, F[1] - F[0], yu[1]);                         \
        float z1 = fmaf(-lam, F[2] - F[1], yu[2]);                         \
        float z2 = fmaf(-lam, F[3] - F[2], yu[3]);                         \
        float z3 = fmaf(-lam, F[4] - F[3], yu[4]);                         \
        if (bcL) { z1 = z2; z0 = z1; }   /* u[0]   = u[1]   + ghost */     \
        if (bcR) { z2 = z1; z3 = z2; }   /* u[N-1] = u[N-2] + ghost */     \
        if (st) { v2f o; o.x = z1; o.y = z2;                               \
                  *reinterpret_cast<v2f*>(dstw - stride) = o; }            \
        /* step 2: update own cells c0, c0+1 */                            \
        v2f za; za.x = z0; za.y = z1;                                      \
        v2f zb; zb.x = z2; zb.y = z3;                                      \
        v2f gza, pza, gzb, pzb;                                            \
        eval_gp2(za, gza, pza);                                            \
        eval_gp2(zb, gzb, pzb);                                            \
        const float G0 = FLUX(gza.x, gza.y, pza.x, pza.y, z0, z1);         \
        const float G1 = FLUX(gza.y, gzb.x, pza.y, pzb.x, z1, z2);         \
        const float G2 = FLUX(gzb.x, gzb.y, pzb.x, pzb.y, z2, z3);         \
        float w0 = fmaf(-lam, G1 - G0, z1);                                \
        float w1 = fmaf(-lam, G2 - G1, z2);                                \
        if (bcL) w0 = w1;                                                  \
        if (bcR) w1 = w0;                                                  \
        uv.x = w0; uv.y = w1;                                              \
        eval_gp2(uv, gv, pv);                                              \
        Us[NXT][tid] = uv; Gs[NXT][tid] = gv; Ps[NXT][tid] = pv;           \
        if (st) *reinterpret_cast<v2f*>(dstw) = uv;                        \
    }                                                                      \
    rem -= 2;                                                              \
    EDGE_BARRIER();                                                        \
} while (0)

    const int S  = nsteps - 1;     // 499 advance steps
    const int P2 = S >> 1;         // 249 super-steps
    int rem = S;                   // steps remaining incl. current super-step
    for (int i = 0; i < P2 / 2; ++i) {
        SUPER(0, 1);
        SUPER(1, 0);
    }
    if (P2 & 1) SUPER(0, 1);
    const int fin = P2 & 1;        // buffer holding t = 2*P2 state

    // ---- odd tail: one single step (everyone runs; junk stays in cone) ----
    if (S & 1) {
        dstw += stride;
        float uL = Us[fin][tl].y, gL = Gs[fin][tl].y, pL = Ps[fin][tl].y;
        float uR = Us[fin][tr].x, gR = Gs[fin][tr].x, pR = Ps[fin][tr].x;
        if (tid == 0)       { uL = uv.x; gL = gv.x; pL = pv.x; }
        if (tid == TPB - 1) { uR = uv.y; gR = gv.y; pR = pv.y; }
        const float fhL = FLUX(gL, gv.x, pL, pv.x, uL, uv.x);
        const float fhM = FLUX(gv.x, gv.y, pv.x, pv.y, uv.x, uv.y);
        const float fhR = FLUX(gv.y, gR, pv.y, pR, uv.y, uR);
        float n0 = fmaf(-lam, fhM - fhL, uv.x);
        float n1 = fmaf(-lam, fhR - fhM, uv.y);
        if (bcL) n0 = n1;
        if (bcR) n1 = n0;
        if (st) { v2f o; o.x = n0; o.y = n1;
                  *reinterpret_cast<v2f*>(dstw) = o; }
    }
#undef SUPER
#undef FLUX
}

extern "C" void kernel_launch(void* const* d_in, const int* in_sizes, int n_in,
                              void* d_out, int out_size, void* d_ws, size_t ws_size,
                              hipStream_t stream) {
    const float* init = (const float*)d_in[0];
    float* out = (float*)d_out;

    const int nbatch = in_sizes[0] / NPTS;       // 128
    const int nsteps = out_size / in_sizes[0];   // 500

    hipLaunchKernelGGL(lxf_split, dim3(2 * nbatch), dim3(TPB), 0, stream,
                       init, out, nbatch, nsteps);
}